// Round 10
// baseline (6962.535 us; speedup 1.0000x reference)
//
#include <hip/hip_runtime.h>
#include <hip/hip_bf16.h>
#include <float.h>

#define SEQ   8192
#define INW   180
#define HID   64
#define G4    256   // 4*HID
#define OUTW  10
#define XW    318   // 10 + 64 + 180 + 64

typedef float f32x4 __attribute__((ext_vector_type(4)));
typedef _Float16 h16x2 __attribute__((ext_vector_type(2)));
typedef unsigned int uint32;

__device__ __forceinline__ float frcp(float x)   { return __builtin_amdgcn_rcpf(x); }
__device__ __forceinline__ float tanhf_f(float x){ return 1.0f - 2.0f * frcp(1.0f + __expf(2.0f * x)); }
__device__ __forceinline__ float gate_act(float x, bool isg) {
    float xx = isg ? 2.0f * x : x;
    float s  = frcp(1.0f + __expf(-xx));
    return isg ? 2.0f * s - 1.0f : s;
}

template<int CTRL>
__device__ __forceinline__ float dpp_bcast(float x) {
    return __int_as_float(__builtin_amdgcn_update_dpp(
        0, __float_as_int(x), CTRL, 0xF, 0xF, true));
}

// v_dot2_f32_f16: acc += a.x*b.x + a.y*b.y  (f32 accumulate, exact products)
__device__ __forceinline__ float fdot2h(h16x2 a, h16x2 b, float c) {
#if __has_builtin(__builtin_amdgcn_fdot2)
    return __builtin_amdgcn_fdot2(a, b, c, false);
#else
    asm("v_dot2_f32_f16 %0, %1, %2, %3" : "=v"(c) : "v"(a), "v"(b), "0"(c));
    return c;
#endif
}

__device__ __forceinline__ h16x2 h2f(float f)   { return __builtin_bit_cast(h16x2, f); }
__device__ __forceinline__ h16x2 h2u(uint32 u)  { return __builtin_bit_cast(h16x2, u); }
__device__ __forceinline__ uint32 pack_h2(float lo, float hi) {
    h16x2 h; h.x = (_Float16)lo; h.y = (_Float16)hi;
    return __builtin_bit_cast(uint32, h);
}

// Opaque 16B load: asm volatile result can't be rematerialized, so barriers
// with "memory" clobber can't turn the weights into per-step reloads.
__device__ __forceinline__ f32x4 opaque_load4(const float* p) {
    f32x4 v;
    asm volatile("global_load_dwordx4 %0, %1, off" : "=v"(v) : "v"(p));
    return v;
}

// ---------------------------------------------------------------------------
// Kernel 0: pack the 3 recurrent matrices to half2 (pairs along K).
// ---------------------------------------------------------------------------
__global__ __launch_bounds__(256) void k_packw(
    const float* __restrict__ Whh0, const float* __restrict__ Wih1,
    const float* __restrict__ Whh1,
    uint32* __restrict__ w0h, uint32* __restrict__ w1ah, uint32* __restrict__ w1bh)
{
    const int gid = blockIdx.x * 256 + threadIdx.x;   // 0 .. 3*8192-1
    const int mat = gid >> 13;
    const int i   = gid & 8191;
    const int r   = i >> 5, k2 = i & 31;
    const float* S = (mat == 0) ? Whh0 : (mat == 1) ? Wih1 : Whh1;
    uint32*      D = (mat == 0) ? w0h  : (mat == 1) ? w1ah : w1bh;
    D[i] = pack_h2(S[r * 64 + 2 * k2], S[r * 64 + 2 * k2 + 1]);
}

// ---------------------------------------------------------------------------
// Kernel 1: pre[s][t] = x[s] @ Wih0[row(t)].T + bih0[row(t)] + bhh0[row(t)]
// row(t) = (t&3)*64 + (t>>2)  (f32, unchanged)
// ---------------------------------------------------------------------------
#define PRE_TS 16
__global__ __launch_bounds__(256) void k_precompute(
    const float* __restrict__ x, const float* __restrict__ Wih0,
    const float* __restrict__ bih0, const float* __restrict__ bhh0,
    float* __restrict__ pre)
{
    __shared__ float xT[INW][PRE_TS];
    const int t  = threadIdx.x;
    const int rr = (t & 3) * 64 + (t >> 2);
    const int s0 = blockIdx.x * PRE_TS;
    for (int i = t; i < PRE_TS * INW; i += 256) {
        int s = i / INW, k = i % INW;
        xT[k][s] = x[s0 * INW + i];
    }
    __syncthreads();
    float acc[PRE_TS];
    const float b = bih0[rr] + bhh0[rr];
#pragma unroll
    for (int s = 0; s < PRE_TS; ++s) acc[s] = b;
    for (int k = 0; k < INW; ++k) {
        float w = Wih0[rr * INW + k];
#pragma unroll
        for (int s = 0; s < PRE_TS; ++s) acc[s] += w * xT[k][s];
    }
#pragma unroll
    for (int s = 0; s < PRE_TS; ++s) pre[(s0 + s) * G4 + t] = acc[s];
}

// 4-accumulator dot over one 16B weight quad (4 half2 = 8 elems)
#define DOT4(A0, A1, A2, A3, WQ, HQ)                         \
    A0 = fdot2h(h2f((WQ).x), h2u((HQ).x), A0);               \
    A1 = fdot2h(h2f((WQ).y), h2u((HQ).y), A1);               \
    A2 = fdot2h(h2f((WQ).z), h2u((HQ).z), A2);               \
    A3 = fdot2h(h2f((WQ).w), h2u((HQ).w), A3);

// ---------------------------------------------------------------------------
// Kernel 2: serial 2-layer LSTM. ONE block, 256 threads (4 waves, 1/SIMD).
// Sequential phases per step (same-step semantics, NO pipeline skew):
//   phase A: h0[s+1] = cell0(x(s), h0[s], c0)     -> barrier
//   phase B: h1[s]   = cell1(h0[s+1], h1[s-1], c1) -> barrier
// Thread q: g=q&3 (i,f,g,o), u=q>>2, r=g*64+u. DPP quad gate-combine.
// Per-thread weights: Whh0 row + Wih1 row + Whh1 row = 96 VGPRs (fp16-packed),
// via opaque loads. 256-thread blocks get a ~140-VGPR budget (measured R1/R2)
// — the only config where the full working set fits without spill.
// ---------------------------------------------------------------------------
__global__ __launch_bounds__(256, 1)
void k_lstm_seq(
    const float* __restrict__ pre,
    const uint32* __restrict__ w0h,    // [G4][32] packed Whh0
    const uint32* __restrict__ w1ah,   // [G4][32] packed Wih1
    const uint32* __restrict__ w1bh,   // [G4][32] packed Whh1
    const float* __restrict__ bih1, const float* __restrict__ bhh1,
    float* __restrict__ oldh, float* __restrict__ h1h)
{
    const int t = threadIdx.x;
    const int q = t, g = q & 3, u = q >> 2, r = g * 64 + u;
    const bool isg = (g == 2);

    __shared__ __attribute__((aligned(16))) uint32 h0p[2][32];
    __shared__ __attribute__((aligned(16))) uint32 h1p[2][32];
    if (t < 32) { h0p[0][t] = 0u; h0p[1][t] = 0u; h1p[0][t] = 0u; h1p[1][t] = 0u; }
    if (t < 64) oldh[t] = 0.0f;

    f32x4 w0[8], wa[8], wb[8];
    {
        const float* W0 = (const float*)(w0h  + r * 32);
        const float* Wa = (const float*)(w1ah + r * 32);
        const float* Wb = (const float*)(w1bh + r * 32);
#pragma unroll
        for (int j = 0; j < 8; ++j) w0[j] = opaque_load4(W0 + 4 * j);
#pragma unroll
        for (int j = 0; j < 8; ++j) wa[j] = opaque_load4(Wa + 4 * j);
#pragma unroll
        for (int j = 0; j < 8; ++j) wb[j] = opaque_load4(Wb + 4 * j);
        asm volatile("s_waitcnt vmcnt(0)" ::: "memory");
    }
    const float b1 = bih1[r] + bhh1[r];
    float c0 = 0.f, c1 = 0.f;
    float preval = pre[q];
    __syncthreads();

    for (int s = 0; s < SEQ; ++s) {
        const int p = s & 1, pn = p ^ 1;

        // ================= phase A: layer-0 =================
        {
            const int sn = (s + 1 < SEQ) ? (s + 1) : s;
            float prenext = pre[sn * G4 + q];

            const uint4* Hp = (const uint4*)&h0p[p][0];
            float a0 = preval, a1 = 0.f, a2 = 0.f, a3 = 0.f;
            {
                uint4 hq0 = Hp[0], hq1 = Hp[1], hq2 = Hp[2], hq3 = Hp[3];
                DOT4(a0, a1, a2, a3, w0[0], hq0)
                DOT4(a0, a1, a2, a3, w0[1], hq1)
                DOT4(a0, a1, a2, a3, w0[2], hq2)
                DOT4(a0, a1, a2, a3, w0[3], hq3)
            }
            __builtin_amdgcn_sched_barrier(0);
            {
                uint4 hq4 = Hp[4], hq5 = Hp[5], hq6 = Hp[6], hq7 = Hp[7];
                DOT4(a0, a1, a2, a3, w0[4], hq4)
                DOT4(a0, a1, a2, a3, w0[5], hq5)
                DOT4(a0, a1, a2, a3, w0[6], hq6)
                DOT4(a0, a1, a2, a3, w0[7], hq7)
            }
            float a  = gate_act((a0 + a1) + (a2 + a3), isg);
            float ai = dpp_bcast<0x00>(a);
            float af = dpp_bcast<0x55>(a);
            float ag = dpp_bcast<0xAA>(a);
            float ao = dpp_bcast<0xFF>(a);
            c0 = fmaf(af, c0, ai * ag);
            float h0n = ao * tanhf_f(c0);
            float hpart = __shfl_xor(h0n, 4);        // partner unit u^1
            if ((q & 7) == 0) h0p[pn][u >> 1] = pack_h2(h0n, hpart);
            if ((q & 3) == 1 && s + 1 < SEQ) oldh[(s + 1) * HID + u] = h0n;
            preval = prenext;
        }
        asm volatile("s_waitcnt lgkmcnt(0)" ::: "memory");
        __builtin_amdgcn_s_barrier();
        asm volatile("" ::: "memory");

        // ================= phase B: layer-1 =================
        {
            const uint4* H0 = (const uint4*)&h0p[pn][0];   // h0[s+1] (new)
            const uint4* H1 = (const uint4*)&h1p[p][0];    // h1[s-1]
            float a0 = b1, a1 = 0.f, a2 = 0.f, a3 = 0.f;
            {
                uint4 hq0 = H0[0], hq1 = H0[1], hq2 = H0[2], hq3 = H0[3];
                DOT4(a0, a1, a2, a3, wa[0], hq0)
                DOT4(a0, a1, a2, a3, wa[1], hq1)
                DOT4(a0, a1, a2, a3, wa[2], hq2)
                DOT4(a0, a1, a2, a3, wa[3], hq3)
            }
            __builtin_amdgcn_sched_barrier(0);
            {
                uint4 hq4 = H0[4], hq5 = H0[5], hq6 = H0[6], hq7 = H0[7];
                DOT4(a0, a1, a2, a3, wa[4], hq4)
                DOT4(a0, a1, a2, a3, wa[5], hq5)
                DOT4(a0, a1, a2, a3, wa[6], hq6)
                DOT4(a0, a1, a2, a3, wa[7], hq7)
            }
            __builtin_amdgcn_sched_barrier(0);
            {
                uint4 hq0 = H1[0], hq1 = H1[1], hq2 = H1[2], hq3 = H1[3];
                DOT4(a0, a1, a2, a3, wb[0], hq0)
                DOT4(a0, a1, a2, a3, wb[1], hq1)
                DOT4(a0, a1, a2, a3, wb[2], hq2)
                DOT4(a0, a1, a2, a3, wb[3], hq3)
            }
            __builtin_amdgcn_sched_barrier(0);
            {
                uint4 hq4 = H1[4], hq5 = H1[5], hq6 = H1[6], hq7 = H1[7];
                DOT4(a0, a1, a2, a3, wb[4], hq4)
                DOT4(a0, a1, a2, a3, wb[5], hq5)
                DOT4(a0, a1, a2, a3, wb[6], hq6)
                DOT4(a0, a1, a2, a3, wb[7], hq7)
            }
            float a  = gate_act((a0 + a1) + (a2 + a3), isg);
            float ai = dpp_bcast<0x00>(a);
            float af = dpp_bcast<0x55>(a);
            float ag = dpp_bcast<0xAA>(a);
            float ao = dpp_bcast<0xFF>(a);
            c1 = fmaf(af, c1, ai * ag);
            float h1n = ao * tanhf_f(c1);
            float hpart = __shfl_xor(h1n, 4);        // partner unit u^1
            if ((q & 7) == 0) h1p[pn][u >> 1] = pack_h2(h1n, hpart);
            if ((q & 3) == 1) h1h[s * HID + u] = h1n;
        }
        asm volatile("s_waitcnt lgkmcnt(0)" ::: "memory");
        __builtin_amdgcn_s_barrier();
        asm volatile("" ::: "memory");
    }
}

// ---------------------------------------------------------------------------
// Kernel 3a/3b: column-wise min/max of oldh (64 cols x 8192 rows)
// ---------------------------------------------------------------------------
__global__ __launch_bounds__(256) void k_minmax1(
    const float* __restrict__ oldh, float* __restrict__ pmn, float* __restrict__ pmx)
{
    const int t = threadIdx.x, b = blockIdx.x;
    float vmn = FLT_MAX, vmx = -FLT_MAX;
    for (int i = t; i < 128 * HID; i += 256) {
        float v = oldh[b * 128 * HID + i];
        vmn = fminf(vmn, v); vmx = fmaxf(vmx, v);
    }
    __shared__ float smn[256], smx[256];
    smn[t] = vmn; smx[t] = vmx;
    __syncthreads();
    if (t < 64) {
        float m0 = fminf(fminf(smn[t], smn[t + 64]), fminf(smn[t + 128], smn[t + 192]));
        float m1 = fmaxf(fmaxf(smx[t], smx[t + 64]), fmaxf(smx[t + 128], smx[t + 192]));
        pmn[b * 64 + t] = m0; pmx[b * 64 + t] = m1;
    }
}

__global__ __launch_bounds__(256) void k_minmax2(
    const float* __restrict__ pmn, const float* __restrict__ pmx,
    float* __restrict__ mn, float* __restrict__ mx)
{
    const int t = threadIdx.x, col = t & 63, chunk = t >> 6;
    float vmn = FLT_MAX, vmx = -FLT_MAX;
    for (int r = chunk * 16; r < chunk * 16 + 16; ++r) {
        vmn = fminf(vmn, pmn[r * 64 + col]);
        vmx = fmaxf(vmx, pmx[r * 64 + col]);
    }
    __shared__ float smn[256], smx[256];
    smn[t] = vmn; smx[t] = vmx;
    __syncthreads();
    if (t < 64) {
        mn[t] = fminf(fminf(smn[t], smn[t + 64]), fminf(smn[t + 128], smn[t + 192]));
        mx[t] = fmaxf(fmaxf(smx[t], smx[t + 64]), fmaxf(smx[t + 128], smx[t + 192]));
    }
}

// ---------------------------------------------------------------------------
// Kernel 4: per-row head + HPM MLP fwd + closed-form VJP. 1 wave per row.
// ---------------------------------------------------------------------------
__global__ __launch_bounds__(256) void k_finalize(
    const float* __restrict__ h1h, const float* __restrict__ oldh,
    const float* __restrict__ x,
    const float* __restrict__ Wlin, const float* __restrict__ blin,
    const float* __restrict__ Wh1,  const float* __restrict__ bh1,
    const float* __restrict__ Wh2,  const float* __restrict__ bh2,
    const float* __restrict__ mn,   const float* __restrict__ mx,
    float* __restrict__ dout)
{
    float* out_o = dout;                          // [SEQ][10]
    float* out_F = dout + SEQ * OUTW;             // [SEQ][180]
    float* out_A = dout + SEQ * (OUTW + INW);     // [SEQ][318]

    const int wave = threadIdx.x >> 6, lane = threadIdx.x & 63;
    const int row  = blockIdx.x * 4 + wave;

    __shared__ float Xs[4][XW + 2];
    __shared__ float h1sh[4][HID];

    h1sh[wave][lane] = h1h[row * HID + lane];
    float mnv = mn[lane], mxv = mx[lane];
    Xs[wave][254 + lane] = (oldh[row * HID + lane] - mnv) * frcp(mxv - mnv + 1e-6f);
    Xs[wave][10 + lane]  = 0.0f;
    for (int c = lane; c < INW; c += 64) Xs[wave][74 + c] = x[row * INW + c];
    __syncthreads();

    if (lane < OUTW) {
        float o = blin[lane];
#pragma unroll
        for (int k = 0; k < HID; ++k) o += Wlin[lane * HID + k] * h1sh[wave][k];
        Xs[wave][lane] = o;
        out_o[row * OUTW + lane] = o;
    }
    __syncthreads();

    float z0 = 0.f, z1 = 0.f, s0 = 0.f, s1 = 0.f;
    for (int c = lane; c < XW; c += 64) {
        float xv = Xs[wave][c];
        z0 += xv * Wh1[c];
        z1 += xv * Wh1[XW + c];
    }
    for (int j = lane; j < INW; j += 64) {
        s0 += Wh2[j * 2 + 0];
        s1 += Wh2[j * 2 + 1];
    }
#pragma unroll
    for (int off = 32; off; off >>= 1) {
        z0 += __shfl_xor(z0, off); z1 += __shfl_xor(z1, off);
        s0 += __shfl_xor(s0, off); s1 += __shfl_xor(s1, off);
    }
    const float t0 = tanhf_f(z0 + bh1[0]);
    const float t1 = tanhf_f(z1 + bh1[1]);
    const float a0 = -s0 * (1.0f - t0 * t0);
    const float a1 = -s1 * (1.0f - t1 * t1);

    for (int c = lane; c < INW; c += 64)
        out_F[row * INW + c] = -(t0 * Wh2[c * 2 + 0] + t1 * Wh2[c * 2 + 1] + bh2[c]);
    for (int c = lane; c < XW; c += 64)
        out_A[row * XW + c] = a0 * Wh1[c] + a1 * Wh1[XW + c];
}

// ---------------------------------------------------------------------------
extern "C" void kernel_launch(void* const* d_in, const int* in_sizes, int n_in,
                              void* d_out, int out_size, void* d_ws, size_t ws_size,
                              hipStream_t stream)
{
    const float* input = (const float*)d_in[0];
    const float* Wih0  = (const float*)d_in[1];
    const float* Whh0  = (const float*)d_in[2];
    const float* bih0  = (const float*)d_in[3];
    const float* bhh0  = (const float*)d_in[4];
    const float* Wih1  = (const float*)d_in[5];
    const float* Whh1  = (const float*)d_in[6];
    const float* bih1  = (const float*)d_in[7];
    const float* bhh1  = (const float*)d_in[8];
    const float* Wlin  = (const float*)d_in[9];
    const float* blin  = (const float*)d_in[10];
    const float* Wh1   = (const float*)d_in[11];
    const float* bh1   = (const float*)d_in[12];
    const float* Wh2   = (const float*)d_in[13];
    const float* bh2   = (const float*)d_in[14];

    float* ws   = (float*)d_ws;
    float* pre  = ws;                         // SEQ*G4
    float* oldh = pre  + SEQ * G4;            // SEQ*HID
    float* h1h  = oldh + SEQ * HID;           // SEQ*HID
    float* pmn  = h1h  + SEQ * HID;           // 64*64
    float* pmx  = pmn  + 64 * 64;             // 64*64
    float* mn   = pmx  + 64 * 64;             // 64
    float* mx   = mn   + 64;                  // 64
    uint32* w0h  = (uint32*)(mx + 64);        // G4*32 packed half2
    uint32* w1ah = w0h  + G4 * 32;
    uint32* w1bh = w1ah + G4 * 32;
    float* out  = (float*)d_out;

    hipLaunchKernelGGL(k_packw, dim3(96), dim3(256), 0, stream,
                       Whh0, Wih1, Whh1, w0h, w1ah, w1bh);
    hipLaunchKernelGGL(k_precompute, dim3(SEQ / PRE_TS), dim3(256), 0, stream,
                       input, Wih0, bih0, bhh0, pre);
    hipLaunchKernelGGL(k_lstm_seq, dim3(1), dim3(256), 0, stream,
                       pre, w0h, w1ah, w1bh, bih1, bhh1, oldh, h1h);
    hipLaunchKernelGGL(k_minmax1, dim3(64), dim3(256), 0, stream, oldh, pmn, pmx);
    hipLaunchKernelGGL(k_minmax2, dim3(1), dim3(256), 0, stream, pmn, pmx, mn, mx);
    hipLaunchKernelGGL(k_finalize, dim3(SEQ / 4), dim3(256), 0, stream,
                       h1h, oldh, input, Wlin, blin, Wh1, bh1, Wh2, bh2, mn, mx, out);
}

// Round 11
// 6319.806 us; speedup vs baseline: 1.1017x; 1.1017x over previous
//
#include <hip/hip_runtime.h>
#include <hip/hip_bf16.h>
#include <float.h>

#define SEQ   8192
#define INW   180
#define HID   64
#define G4    256   // 4*HID
#define OUTW  10
#define XW    318   // 10 + 64 + 180 + 64

typedef float f32x4 __attribute__((ext_vector_type(4)));
typedef _Float16 h16x2 __attribute__((ext_vector_type(2)));
typedef unsigned int uint32;

__device__ __forceinline__ float frcp(float x)   { return __builtin_amdgcn_rcpf(x); }
__device__ __forceinline__ float tanhf_f(float x){ return 1.0f - 2.0f * frcp(1.0f + __expf(2.0f * x)); }
__device__ __forceinline__ float gate_act(float x, bool isg) {
    float xx = isg ? 2.0f * x : x;
    float s  = frcp(1.0f + __expf(-xx));
    return isg ? 2.0f * s - 1.0f : s;
}

template<int CTRL>
__device__ __forceinline__ float dpp_bcast(float x) {
    return __int_as_float(__builtin_amdgcn_update_dpp(
        0, __float_as_int(x), CTRL, 0xF, 0xF, true));
}

// v_dot2_f32_f16: acc += a.x*b.x + a.y*b.y  (f32 accumulate, exact products)
__device__ __forceinline__ float fdot2h(h16x2 a, h16x2 b, float c) {
#if __has_builtin(__builtin_amdgcn_fdot2)
    return __builtin_amdgcn_fdot2(a, b, c, false);
#else
    asm("v_dot2_f32_f16 %0, %1, %2, %3" : "=v"(c) : "v"(a), "v"(b), "0"(c));
    return c;
#endif
}

__device__ __forceinline__ h16x2 h2f(float f)   { return __builtin_bit_cast(h16x2, f); }
__device__ __forceinline__ h16x2 h2u(uint32 u)  { return __builtin_bit_cast(h16x2, u); }
__device__ __forceinline__ uint32 pack_h2(float lo, float hi) {
    h16x2 h; h.x = (_Float16)lo; h.y = (_Float16)hi;
    return __builtin_bit_cast(uint32, h);
}

// Opaque 16B load: asm volatile result can't be rematerialized, so barriers
// with "memory" clobber can't turn the weights into per-step reloads.
__device__ __forceinline__ f32x4 opaque_load4(const float* p) {
    f32x4 v;
    asm volatile("global_load_dwordx4 %0, %1, off" : "=v"(v) : "v"(p));
    return v;
}

// ---------------------------------------------------------------------------
// Kernel 0: pack the 3 recurrent matrices to half2 (pairs along K).
// ---------------------------------------------------------------------------
__global__ __launch_bounds__(256) void k_packw(
    const float* __restrict__ Whh0, const float* __restrict__ Wih1,
    const float* __restrict__ Whh1,
    uint32* __restrict__ w0h, uint32* __restrict__ w1ah, uint32* __restrict__ w1bh)
{
    const int gid = blockIdx.x * 256 + threadIdx.x;   // 0 .. 3*8192-1
    const int mat = gid >> 13;
    const int i   = gid & 8191;
    const int r   = i >> 5, k2 = i & 31;
    const float* S = (mat == 0) ? Whh0 : (mat == 1) ? Wih1 : Whh1;
    uint32*      D = (mat == 0) ? w0h  : (mat == 1) ? w1ah : w1bh;
    D[i] = pack_h2(S[r * 64 + 2 * k2], S[r * 64 + 2 * k2 + 1]);
}

// ---------------------------------------------------------------------------
// Kernel 1: pre[s][t] = x[s] @ Wih0[row(t)].T + bih0[row(t)] + bhh0[row(t)]
// row(t) = (t&3)*64 + (t>>2)  (f32, unchanged)
// ---------------------------------------------------------------------------
#define PRE_TS 16
__global__ __launch_bounds__(256) void k_precompute(
    const float* __restrict__ x, const float* __restrict__ Wih0,
    const float* __restrict__ bih0, const float* __restrict__ bhh0,
    float* __restrict__ pre)
{
    __shared__ float xT[INW][PRE_TS];
    const int t  = threadIdx.x;
    const int rr = (t & 3) * 64 + (t >> 2);
    const int s0 = blockIdx.x * PRE_TS;
    for (int i = t; i < PRE_TS * INW; i += 256) {
        int s = i / INW, k = i % INW;
        xT[k][s] = x[s0 * INW + i];
    }
    __syncthreads();
    float acc[PRE_TS];
    const float b = bih0[rr] + bhh0[rr];
#pragma unroll
    for (int s = 0; s < PRE_TS; ++s) acc[s] = b;
    for (int k = 0; k < INW; ++k) {
        float w = Wih0[rr * INW + k];
#pragma unroll
        for (int s = 0; s < PRE_TS; ++s) acc[s] += w * xT[k][s];
    }
#pragma unroll
    for (int s = 0; s < PRE_TS; ++s) pre[(s0 + s) * G4 + t] = acc[s];
}

// 4-accumulator dot over one 16B weight quad (4 half2 = 8 elems)
#define DOT4(A0, A1, A2, A3, WQ, HQ)                         \
    A0 = fdot2h(h2f((WQ).x), h2u((HQ).x), A0);               \
    A1 = fdot2h(h2f((WQ).y), h2u((HQ).y), A1);               \
    A2 = fdot2h(h2f((WQ).z), h2u((HQ).z), A2);               \
    A3 = fdot2h(h2f((WQ).w), h2u((HQ).w), A3);

// full 8-quad dot (two 4-quad windows, sched_barrier caps staging regs)
#define DOT8(A0, A1, A2, A3, W, HP)                          \
    {                                                        \
        uint4 hq0 = (HP)[0], hq1 = (HP)[1], hq2 = (HP)[2], hq3 = (HP)[3]; \
        DOT4(A0, A1, A2, A3, (W)[0], hq0)                    \
        DOT4(A0, A1, A2, A3, (W)[1], hq1)                    \
        DOT4(A0, A1, A2, A3, (W)[2], hq2)                    \
        DOT4(A0, A1, A2, A3, (W)[3], hq3)                    \
    }                                                        \
    __builtin_amdgcn_sched_barrier(0);                       \
    {                                                        \
        uint4 hq4 = (HP)[4], hq5 = (HP)[5], hq6 = (HP)[6], hq7 = (HP)[7]; \
        DOT4(A0, A1, A2, A3, (W)[4], hq4)                    \
        DOT4(A0, A1, A2, A3, (W)[5], hq5)                    \
        DOT4(A0, A1, A2, A3, (W)[6], hq6)                    \
        DOT4(A0, A1, A2, A3, (W)[7], hq7)                    \
    }

// ---------------------------------------------------------------------------
// Kernel 2: serial 2-layer LSTM. ONE block, 768 threads (12 waves, 3/SIMD).
// ONE weight row per thread (8 fp16 quads = 32 VGPR — fits the ~68-VGPR
// grant observed at this block size; R4-R10's 64-96dw/thread always spilled).
//   grp0 (t<256):   Whh0 row.  phase A: h0[s+1] = cell0(x[s], h0[s], c0)
//   grp2 (t>=512):  Whh1 row.  phase A: partial[r] = Whh1_r . h1[s-1]
//   grp1 (256..511):Wih1 row.  phase B: z = Wih1_r . h0[s+1] + partial[r] + b1
//                               -> gates (DPP quad) -> h1[s], c1
// Sequential phases per step, 2 barriers (R10-verified same-step semantics).
// Thread i8=t&255 = 4u+g: g=gate, u=unit, weight row r=g*64+u.
// ---------------------------------------------------------------------------
__global__ __launch_bounds__(768, 1)
void k_lstm_seq(
    const float* __restrict__ pre,
    const uint32* __restrict__ w0h,    // [G4][32] packed Whh0
    const uint32* __restrict__ w1ah,   // [G4][32] packed Wih1
    const uint32* __restrict__ w1bh,   // [G4][32] packed Whh1
    const float* __restrict__ bih1, const float* __restrict__ bhh1,
    float* __restrict__ oldh, float* __restrict__ h1h)
{
    const int t   = threadIdx.x;
    const int grp = t >> 8;           // 0: Whh0, 1: Wih1, 2: Whh1
    const int i8  = t & 255;
    const int g   = i8 & 3, u = i8 >> 2, r = g * 64 + u;
    const bool isg = (g == 2);

    __shared__ __attribute__((aligned(16))) uint32 h0p[2][32];
    __shared__ __attribute__((aligned(16))) uint32 h1p[2][32];
    __shared__ float partial[256];
    if (t < 32) { h0p[0][t] = 0u; h0p[1][t] = 0u; h1p[0][t] = 0u; h1p[1][t] = 0u; }
    if (t < 64) oldh[t] = 0.0f;

    f32x4 w[8];
    {
        const uint32* Wsrc = (grp == 0) ? w0h : (grp == 1) ? w1ah : w1bh;
        const float*  W    = (const float*)(Wsrc + r * 32);
#pragma unroll
        for (int j = 0; j < 8; ++j) w[j] = opaque_load4(W + 4 * j);
        asm volatile("s_waitcnt vmcnt(0)" ::: "memory");
    }
    const float b1 = (grp == 1) ? (bih1[r] + bhh1[r]) : 0.0f;
    float cc = 0.0f;                          // c0 (grp0) / c1 (grp1)
    float preval = (grp == 0) ? pre[i8] : 0.0f;
    __syncthreads();

    for (int s = 0; s < SEQ; ++s) {
        const int p = s & 1, pn = p ^ 1;

        // ================= phase A =================
        if (grp == 0) {
            const int sn = (s + 1 < SEQ) ? (s + 1) : s;
            float prenext = pre[sn * G4 + i8];

            const uint4* Hp = (const uint4*)&h0p[p][0];      // h0[s]
            float a0 = preval, a1 = 0.f, a2 = 0.f, a3 = 0.f;
            DOT8(a0, a1, a2, a3, w, Hp)
            float a  = gate_act((a0 + a1) + (a2 + a3), isg);
            float ai = dpp_bcast<0x00>(a);
            float af = dpp_bcast<0x55>(a);
            float ag = dpp_bcast<0xAA>(a);
            float ao = dpp_bcast<0xFF>(a);
            cc = fmaf(af, cc, ai * ag);
            float h0n = ao * tanhf_f(cc);
            float hpart = __shfl_xor(h0n, 4);                // unit u^1
            if ((i8 & 7) == 0) h0p[pn][u >> 1] = pack_h2(h0n, hpart);
            if ((i8 & 3) == 1 && s + 1 < SEQ) oldh[(s + 1) * HID + u] = h0n;
            preval = prenext;
        } else if (grp == 2) {
            const uint4* Hp = (const uint4*)&h1p[p][0];      // h1[s-1]
            float a0 = 0.f, a1 = 0.f, a2 = 0.f, a3 = 0.f;
            DOT8(a0, a1, a2, a3, w, Hp)
            partial[i8] = (a0 + a1) + (a2 + a3);
        }
        asm volatile("s_waitcnt lgkmcnt(0)" ::: "memory");
        __builtin_amdgcn_s_barrier();
        asm volatile("" ::: "memory");

        // ================= phase B =================
        if (grp == 1) {
            const uint4* Hp = (const uint4*)&h0p[pn][0];     // h0[s+1] (new)
            float a0 = b1, a1 = 0.f, a2 = 0.f, a3 = 0.f;
            DOT8(a0, a1, a2, a3, w, Hp)
            float z = ((a0 + a1) + (a2 + a3)) + partial[i8];
            float a  = gate_act(z, isg);
            float ai = dpp_bcast<0x00>(a);
            float af = dpp_bcast<0x55>(a);
            float ag = dpp_bcast<0xAA>(a);
            float ao = dpp_bcast<0xFF>(a);
            cc = fmaf(af, cc, ai * ag);
            float h1n = ao * tanhf_f(cc);
            float hpart = __shfl_xor(h1n, 4);                // unit u^1
            if ((i8 & 7) == 0) h1p[pn][u >> 1] = pack_h2(h1n, hpart);
            if ((i8 & 3) == 1) h1h[s * HID + u] = h1n;
        }
        asm volatile("s_waitcnt lgkmcnt(0)" ::: "memory");
        __builtin_amdgcn_s_barrier();
        asm volatile("" ::: "memory");
    }
}

// ---------------------------------------------------------------------------
// Kernel 3a/3b: column-wise min/max of oldh (64 cols x 8192 rows)
// ---------------------------------------------------------------------------
__global__ __launch_bounds__(256) void k_minmax1(
    const float* __restrict__ oldh, float* __restrict__ pmn, float* __restrict__ pmx)
{
    const int t = threadIdx.x, b = blockIdx.x;
    float vmn = FLT_MAX, vmx = -FLT_MAX;
    for (int i = t; i < 128 * HID; i += 256) {
        float v = oldh[b * 128 * HID + i];
        vmn = fminf(vmn, v); vmx = fmaxf(vmx, v);
    }
    __shared__ float smn[256], smx[256];
    smn[t] = vmn; smx[t] = vmx;
    __syncthreads();
    if (t < 64) {
        float m0 = fminf(fminf(smn[t], smn[t + 64]), fminf(smn[t + 128], smn[t + 192]));
        float m1 = fmaxf(fmaxf(smx[t], smx[t + 64]), fmaxf(smx[t + 128], smx[t + 192]));
        pmn[b * 64 + t] = m0; pmx[b * 64 + t] = m1;
    }
}

__global__ __launch_bounds__(256) void k_minmax2(
    const float* __restrict__ pmn, const float* __restrict__ pmx,
    float* __restrict__ mn, float* __restrict__ mx)
{
    const int t = threadIdx.x, col = t & 63, chunk = t >> 6;
    float vmn = FLT_MAX, vmx = -FLT_MAX;
    for (int r = chunk * 16; r < chunk * 16 + 16; ++r) {
        vmn = fminf(vmn, pmn[r * 64 + col]);
        vmx = fmaxf(vmx, pmx[r * 64 + col]);
    }
    __shared__ float smn[256], smx[256];
    smn[t] = vmn; smx[t] = vmx;
    __syncthreads();
    if (t < 64) {
        mn[t] = fminf(fminf(smn[t], smn[t + 64]), fminf(smn[t + 128], smn[t + 192]));
        mx[t] = fmaxf(fmaxf(smx[t], smx[t + 64]), fmaxf(smx[t + 128], smx[t + 192]));
    }
}

// ---------------------------------------------------------------------------
// Kernel 4: per-row head + HPM MLP fwd + closed-form VJP. 1 wave per row.
// ---------------------------------------------------------------------------
__global__ __launch_bounds__(256) void k_finalize(
    const float* __restrict__ h1h, const float* __restrict__ oldh,
    const float* __restrict__ x,
    const float* __restrict__ Wlin, const float* __restrict__ blin,
    const float* __restrict__ Wh1,  const float* __restrict__ bh1,
    const float* __restrict__ Wh2,  const float* __restrict__ bh2,
    const float* __restrict__ mn,   const float* __restrict__ mx,
    float* __restrict__ dout)
{
    float* out_o = dout;                          // [SEQ][10]
    float* out_F = dout + SEQ * OUTW;             // [SEQ][180]
    float* out_A = dout + SEQ * (OUTW + INW);     // [SEQ][318]

    const int wave = threadIdx.x >> 6, lane = threadIdx.x & 63;
    const int row  = blockIdx.x * 4 + wave;

    __shared__ float Xs[4][XW + 2];
    __shared__ float h1sh[4][HID];

    h1sh[wave][lane] = h1h[row * HID + lane];
    float mnv = mn[lane], mxv = mx[lane];
    Xs[wave][254 + lane] = (oldh[row * HID + lane] - mnv) * frcp(mxv - mnv + 1e-6f);
    Xs[wave][10 + lane]  = 0.0f;
    for (int c = lane; c < INW; c += 64) Xs[wave][74 + c] = x[row * INW + c];
    __syncthreads();

    if (lane < OUTW) {
        float o = blin[lane];
#pragma unroll
        for (int k = 0; k < HID; ++k) o += Wlin[lane * HID + k] * h1sh[wave][k];
        Xs[wave][lane] = o;
        out_o[row * OUTW + lane] = o;
    }
    __syncthreads();

    float z0 = 0.f, z1 = 0.f, s0 = 0.f, s1 = 0.f;
    for (int c = lane; c < XW; c += 64) {
        float xv = Xs[wave][c];
        z0 += xv * Wh1[c];
        z1 += xv * Wh1[XW + c];
    }
    for (int j = lane; j < INW; j += 64) {
        s0 += Wh2[j * 2 + 0];
        s1 += Wh2[j * 2 + 1];
    }
#pragma unroll
    for (int off = 32; off; off >>= 1) {
        z0 += __shfl_xor(z0, off); z1 += __shfl_xor(z1, off);
        s0 += __shfl_xor(s0, off); s1 += __shfl_xor(s1, off);
    }
    const float t0 = tanhf_f(z0 + bh1[0]);
    const float t1 = tanhf_f(z1 + bh1[1]);
    const float a0 = -s0 * (1.0f - t0 * t0);
    const float a1 = -s1 * (1.0f - t1 * t1);

    for (int c = lane; c < INW; c += 64)
        out_F[row * INW + c] = -(t0 * Wh2[c * 2 + 0] + t1 * Wh2[c * 2 + 1] + bh2[c]);
    for (int c = lane; c < XW; c += 64)
        out_A[row * XW + c] = a0 * Wh1[c] + a1 * Wh1[XW + c];
}

// ---------------------------------------------------------------------------
extern "C" void kernel_launch(void* const* d_in, const int* in_sizes, int n_in,
                              void* d_out, int out_size, void* d_ws, size_t ws_size,
                              hipStream_t stream)
{
    const float* input = (const float*)d_in[0];
    const float* Wih0  = (const float*)d_in[1];
    const float* Whh0  = (const float*)d_in[2];
    const float* bih0  = (const float*)d_in[3];
    const float* bhh0  = (const float*)d_in[4];
    const float* Wih1  = (const float*)d_in[5];
    const float* Whh1  = (const float*)d_in[6];
    const float* bih1  = (const float*)d_in[7];
    const float* bhh1  = (const float*)d_in[8];
    const float* Wlin  = (const float*)d_in[9];
    const float* blin  = (const float*)d_in[10];
    const float* Wh1   = (const float*)d_in[11];
    const float* bh1   = (const float*)d_in[12];
    const float* Wh2   = (const float*)d_in[13];
    const float* bh2   = (const float*)d_in[14];

    float* ws   = (float*)d_ws;
    float* pre  = ws;                         // SEQ*G4
    float* oldh = pre  + SEQ * G4;            // SEQ*HID
    float* h1h  = oldh + SEQ * HID;           // SEQ*HID
    float* pmn  = h1h  + SEQ * HID;           // 64*64
    float* pmx  = pmn  + 64 * 64;             // 64*64
    float* mn   = pmx  + 64 * 64;             // 64
    float* mx   = mn   + 64;                  // 64
    uint32* w0h  = (uint32*)(mx + 64);        // G4*32 packed half2
    uint32* w1ah = w0h  + G4 * 32;
    uint32* w1bh = w1ah + G4 * 32;
    float* out  = (float*)d_out;

    hipLaunchKernelGGL(k_packw, dim3(96), dim3(256), 0, stream,
                       Whh0, Wih1, Whh1, w0h, w1ah, w1bh);
    hipLaunchKernelGGL(k_precompute, dim3(SEQ / PRE_TS), dim3(256), 0, stream,
                       input, Wih0, bih0, bhh0, pre);
    hipLaunchKernelGGL(k_lstm_seq, dim3(1), dim3(768), 0, stream,
                       pre, w0h, w1ah, w1bh, bih1, bhh1, oldh, h1h);
    hipLaunchKernelGGL(k_minmax1, dim3(64), dim3(256), 0, stream, oldh, pmn, pmx);
    hipLaunchKernelGGL(k_minmax2, dim3(1), dim3(256), 0, stream, pmn, pmx, mn, mx);
    hipLaunchKernelGGL(k_finalize, dim3(SEQ / 4), dim3(256), 0, stream,
                       h1h, oldh, input, Wlin, blin, Wh1, bh1, Wh2, bh2, mn, mx, out);
}